// Round 3
// baseline (237.565 us; speedup 1.0000x reference)
//
#include <hip/hip_runtime.h>

// LNCC DEBUG1: num = (tp_sum - (p_sum/729)*t_sum)^2 + 1e-5, 9^3 box sums, SAME zero pad.
//
// R7 = R3 structure (2 LDS-only barriers/plane, 30 KB single-buffered LDS — best
// measured at 112 us) with per-plane VALU cuts. R6 proved barrier count was NOT the
// bottleneck (1-barrier pipeline regressed to 124 us; occupancy/VALUBusy unchanged):
// the kernel is instruction-issue bound. So R7 cuts instructions:
//  (a) fa/fc prefetch regs are loop-carried, zeroed ONCE pre-loop; per-plane zeroing
//      (24 v_movs/wave) only under a block-uniform !zok branch (z-boundary planes,
//      <=4 per block). Persistently-inactive lanes (x/y OOB) never load, so their
//      one-time zeros persist. Interior planes: loads just overwrite.
//  (b) ROWSUM consumes fa directly at iteration top; next-plane loads issue right
//      after (register dependence orders them). The cur<-fa copy (12 v_movs/plane)
//      and the cur registers are gone. Prefetch still spans both barriers + colsum +
//      gather before its vmcnt wait at the next rowsum.
//  (c) incremental output pointer (obp += plane) instead of per-plane mad_u64.

#define N 192
#define RSTRIDE 46   // rowT stride: 2-way banks (free) + 8B-aligned float2 reads

// LDS-only barrier: drain LDS ops, then barrier. No vmcnt drain (prefetch stays in flight).
#define LDS_BARRIER() asm volatile("s_waitcnt lgkmcnt(0)\n\ts_barrier" ::: "memory")

__global__ __launch_bounds__(1024, 4)
void lncc_kernel(const float* __restrict__ t_in,
                 const float* __restrict__ p_in,
                 float* __restrict__ out)
{
    // rowT[f][x][ry]: transposed x-blurred row sums (single-buffered)
    __shared__ __align__(16) float rowT[3 * 32 * RSTRIDE];   // 17.3 KB
    // pcol[f][y][x]: per-plane 2D (9x9) box sums
    __shared__ float pcol[3 * 32 * 32];                      // 12 KB

    // ---- work assignment: 512 blocks = 72 xy tiles x {8 or 7} z-chunks ----
    const int bid = blockIdx.x;
    int xy, Z, z0;
    if (bid < 64) {                 // tiles 0..7: 8 chunks of Z=24
        xy = bid >> 3;
        Z  = 24;
        z0 = (bid & 7) * 24;
    } else {                        // tiles 8..71: 7 chunks (28,28,28,27,27,27,27)
        const int q  = bid - 64;
        xy = 8 + q / 7;
        const int zi = q % 7;
        if (zi < 3) { Z = 28; z0 = zi * 28; }
        else        { Z = 27; z0 = 84 + (zi - 3) * 27; }
    }
    const int b  = xy / 36;
    const int t6 = xy % 36;
    const int y0 = (t6 / 6) * 32, x0 = (t6 % 6) * 32;
    const int tid = threadIdx.x;

    // ---- L (row-sum) decode: 3 fields x 40 rows x 8 x-quads = 960 slots (15 waves)
    const int  lf   = tid / 320;          // 0=t 1=p 2=tp (wave-uniform: 320=5*64)
    const int  ls   = tid - lf * 320;
    const int  lry  = ls >> 3;            // raw row 0..39
    const int  lxq  = ls & 7;             // x quad 0..7
    const int  lgy  = y0 - 4 + lry;
    const int  lgx0 = x0 - 4 + 4 * lxq;   // 16B-aligned quad base
    const bool lactive = (tid < 960);
    const bool lyok = ((unsigned)lgy < (unsigned)N);
    const bool lv   = lactive && lyok;
    // loop-invariant x validity per quad (persistent: invalid quads never load)
    const bool q0ok = ((unsigned)lgx0 < (unsigned)N);
    const bool q1ok = ((unsigned)(lgx0 + 4) < (unsigned)N);
    const bool q2ok = ((unsigned)(lgx0 + 8) < (unsigned)N);

    // ---- C (col-sum) decode: 3 fields x 8 y-quads x 32 x = 768 slots (12 waves)
    const int  cf  = tid >> 8;
    const int  cyq = (tid >> 5) & 7;
    const int  cx  = tid & 31;
    const bool cactive = (tid < 768);

    // ---- G decode: thread owns output column (gx,gy)
    const int gx = tid & 31;
    const int gy = tid >> 5;

    const size_t plane = (size_t)N * N;
    const float* tb = t_in + (size_t)b * N * plane;
    const float* pb = p_in + (size_t)b * N * plane;

    // loop-invariant row base pointers (y clamped; loads guarded by lv)
    const int lgyc = lyok ? lgy : 0;
    const float* const trow = tb + (size_t)lgyc * N;
    const float* const prow = pb + (size_t)lgyc * N;
    const float* const arow = (lf == 1) ? prow : trow;   // a-source select hoisted

    // per-thread LDS base pointers
    float* const       wpA = &rowT[(lf * 32 + 4 * lxq) * RSTRIDE + lry];
    const float* const rbB = &rowT[(cf * 32 + cx) * RSTRIDE + 4 * cyq];
    float* const       pcB = &pcol[cf * 1024 + (4 * cyq) * 32 + cx];
    const float* const pgC = &pcol[gy * 32 + gx];

    // incremental output pointer: at iteration i (after increment at iter end),
    // obp points at z-slice z0 + i - 8.
    float* obp = out + (size_t)b * N * plane
                     + (size_t)(y0 + gy) * N + (x0 + gx)
                     + (long)(z0 - 8) * (long)plane;

    float ring_t[9], ring_p[9], ring_tp[9];
    float sum_t = 0.f, sum_p = 0.f, sum_tp = 0.f;
    #pragma unroll
    for (int i = 0; i < 9; ++i) { ring_t[i] = 0.f; ring_p[i] = 0.f; ring_tp[i] = 0.f; }

    const float4 z4 = make_float4(0.f, 0.f, 0.f, 0.f);
    // loop-carried prefetch registers: hold plane i data at iteration-i top.
    float4 fa0 = z4, fa1 = z4, fa2 = z4, fc0 = z4, fc1 = z4, fc2 = z4;

    // ---- prologue: load plane 0 (zeros persist for OOB/inactive lanes) ----
    long zoff = (long)(z0 - 4) * (long)plane;
    if (((unsigned)(z0 - 4) < (unsigned)N) && lv) {
        const float* ar = arow + zoff;
        const float* cr = prow + zoff;
        if (q0ok) { fa0 = *(const float4*)(ar + lgx0);     if (lf == 2) fc0 = *(const float4*)(cr + lgx0); }
        if (q1ok) { fa1 = *(const float4*)(ar + lgx0 + 4); if (lf == 2) fc1 = *(const float4*)(cr + lgx0 + 4); }
        if (q2ok) { fa2 = *(const float4*)(ar + lgx0 + 8); if (lf == 2) fc2 = *(const float4*)(cr + lgx0 + 8); }
    }

    #pragma unroll 1
    for (int k = 0; k < 4; ++k) {
      #pragma unroll
      for (int r = 0; r < 9; ++r) {
        const int i  = k * 9 + r;
        const int zp = z0 - 4 + i;           // plane i global z
        const bool vi = (i < Z + 8) && ((unsigned)zp < (unsigned)N);

        // ---- 1. RowSum(plane i) directly from fa/fc -> rowT ----
        if (vi && lactive) {
            float v0, v1, v2, v3, v4, v5, v6, v7, v8, v9, v10, v11;
            if (lf == 2) {       // wave-uniform branch: only tp waves pay the muls
                v0 = fa0.x * fc0.x; v1 = fa0.y * fc0.y; v2  = fa0.z * fc0.z; v3  = fa0.w * fc0.w;
                v4 = fa1.x * fc1.x; v5 = fa1.y * fc1.y; v6  = fa1.z * fc1.z; v7  = fa1.w * fc1.w;
                v8 = fa2.x * fc2.x; v9 = fa2.y * fc2.y; v10 = fa2.z * fc2.z; v11 = fa2.w * fc2.w;
            } else {
                v0 = fa0.x; v1 = fa0.y; v2  = fa0.z; v3  = fa0.w;
                v4 = fa1.x; v5 = fa1.y; v6  = fa1.z; v7  = fa1.w;
                v8 = fa2.x; v9 = fa2.y; v10 = fa2.z; v11 = fa2.w;
            }
            float s0 = ((v0 + v1) + (v2 + v3)) + ((v4 + v5) + (v6 + v7)) + v8;
            float s1 = s0 - v0 + v9;
            float s2 = s1 - v1 + v10;
            float s3 = s2 - v2 + v11;
            wpA[0]           = s0;
            wpA[RSTRIDE]     = s1;
            wpA[2 * RSTRIDE] = s2;
            wpA[3 * RSTRIDE] = s3;
        }

        // ---- 2. issue loads for plane i+1 (fa consumed above; regs now free) ----
        zoff += (long)plane;                 // (z0 - 3 + i) * plane
        {
            const bool zok = (i + 1 < Z + 8) && ((unsigned)(z0 - 3 + i) < (unsigned)N);
            if (zok) {
                if (lv) {
                    const float* ar = arow + zoff;
                    const float* cr = prow + zoff;
                    if (q0ok) { fa0 = *(const float4*)(ar + lgx0);     if (lf == 2) fc0 = *(const float4*)(cr + lgx0); }
                    if (q1ok) { fa1 = *(const float4*)(ar + lgx0 + 4); if (lf == 2) fc1 = *(const float4*)(cr + lgx0 + 4); }
                    if (q2ok) { fa2 = *(const float4*)(ar + lgx0 + 8); if (lf == 2) fc2 = *(const float4*)(cr + lgx0 + 8); }
                }
            } else {   // block-uniform boundary branch: <=4 planes per block
                fa0 = z4; fa1 = z4; fa2 = z4; fc0 = z4; fc1 = z4; fc2 = z4;
            }
        }
        LDS_BARRIER();

        // ---- 3. ColSum(plane i): rowT -> pcol ----
        if (vi && cactive) {
            const float2 u0 = *(const float2*)(rbB + 0);
            const float2 u1 = *(const float2*)(rbB + 2);
            const float2 u2 = *(const float2*)(rbB + 4);
            const float2 u3 = *(const float2*)(rbB + 6);
            const float2 u4 = *(const float2*)(rbB + 8);
            const float2 u5 = *(const float2*)(rbB + 10);
            const float w0 = u0.x, w1 = u0.y, w2  = u1.x, w3  = u1.y;
            const float w4 = u2.x, w5 = u2.y, w6  = u3.x, w7  = u3.y;
            const float w8 = u4.x, w9 = u4.y, w10 = u5.x, w11 = u5.y;
            float c0 = ((w0 + w1) + (w2 + w3)) + ((w4 + w5) + (w6 + w7)) + w8;
            float c1 = c0 - w0 + w9;
            float c2 = c1 - w1 + w10;
            float c3 = c2 - w2 + w11;
            pcB[0]  = c0;
            pcB[32] = c1;
            pcB[64] = c2;
            pcB[96] = c3;
        }
        LDS_BARRIER();

        // ---- 4. Gather(plane i), z-ring (slot r == i%9), output ----
        float Pt = 0.f, Pp = 0.f, Ptp = 0.f;
        if (vi) {
            Pt  = pgC[0];
            Pp  = pgC[1024];
            Ptp = pgC[2048];
        }
        sum_t  += Pt  - ring_t[r];  ring_t[r]  = Pt;
        sum_p  += Pp  - ring_p[r];  ring_p[r]  = Pp;
        sum_tp += Ptp - ring_tp[r]; ring_tp[r] = Ptp;
        if (i >= 8 && i < Z + 8) {
            const float cross = sum_tp - (sum_p * (1.0f / 729.0f)) * sum_t;
            *obp = cross * cross + 1e-5f;
        }
        obp += plane;
      }
    }
}

extern "C" void kernel_launch(void* const* d_in, const int* in_sizes, int n_in,
                              void* d_out, int out_size, void* d_ws, size_t ws_size,
                              hipStream_t stream) {
    const float* y_true = (const float*)d_in[0];
    const float* y_pred = (const float*)d_in[1];
    float* out = (float*)d_out;
    dim3 grid(512);
    dim3 block(1024);
    hipLaunchKernelGGL(lncc_kernel, grid, block, 0, stream, y_true, y_pred, out);
}

// Round 4
// 210.331 us; speedup vs baseline: 1.1295x; 1.1295x over previous
//
#include <hip/hip_runtime.h>

// LNCC DEBUG1: num = (tp_sum - (p_sum/729)*t_sum)^2 + 1e-5, 9^3 box sums, SAME zero pad.
//
// R8 = champion R3 structure VERBATIM (112 us: 2 LDS-only barriers/plane, 30 KB
// single-buffered LDS, register prefetch issued at step 1, rowsum from finalized
// `cur`, vmcnt-wait + lf==2 multiply in the post-barrier2 shadow at step 5).
// R6 (1-barrier pipeline, +11%) and R7 (top-consume + branchy rowsum, +21%) proved
// the per-plane cost is a barrier convoy: plane time = slowest wave's
// (wait -> rowsum -> bar1 -> colsum -> bar2); R3 keeps the pre-barrier segments
// minimal and both restructures lengthened them. So: restore R3 exactly.
// ONLY change vs R3: loop-invariant hoisting of the row base pointers
// (trow/prow with lgy*N folded, y-clamped) and the wave-uniform a-source select
// (arow), so step 1 computes ar/cr with one uniform zn*plane add — no control-flow
// or consume-point changes.

#define N 192
#define RSTRIDE 46   // rowT stride: 2-way banks (free) + 8B-aligned float2 reads

// LDS-only barrier: drain LDS ops, then barrier. No vmcnt drain (prefetch stays in flight).
#define LDS_BARRIER() asm volatile("s_waitcnt lgkmcnt(0)\n\ts_barrier" ::: "memory")

__global__ __launch_bounds__(1024, 4)
void lncc_kernel(const float* __restrict__ t_in,
                 const float* __restrict__ p_in,
                 float* __restrict__ out)
{
    // rowT[f][x][ry]: transposed x-blurred row sums (single-buffered)
    __shared__ __align__(16) float rowT[3 * 32 * RSTRIDE];   // 17.3 KB
    // pcol[f][y][x]: per-plane 2D (9x9) box sums
    __shared__ float pcol[3 * 32 * 32];                      // 12 KB

    // ---- work assignment: 512 blocks = 72 xy tiles x {8 or 7} z-chunks ----
    const int bid = blockIdx.x;
    int xy, Z, z0;
    if (bid < 64) {                 // tiles 0..7: 8 chunks of Z=24
        xy = bid >> 3;
        Z  = 24;
        z0 = (bid & 7) * 24;
    } else {                        // tiles 8..71: 7 chunks (28,28,28,27,27,27,27)
        const int q  = bid - 64;
        xy = 8 + q / 7;
        const int zi = q % 7;
        if (zi < 3) { Z = 28; z0 = zi * 28; }
        else        { Z = 27; z0 = 84 + (zi - 3) * 27; }
    }
    const int b  = xy / 36;
    const int t6 = xy % 36;
    const int y0 = (t6 / 6) * 32, x0 = (t6 % 6) * 32;
    const int tid = threadIdx.x;

    // ---- L (row-sum) decode: 3 fields x 40 rows x 8 x-quads = 960 slots (15 waves)
    const int  lf   = tid / 320;          // 0=t 1=p 2=tp (wave-uniform: 320=5*64)
    const int  ls   = tid - lf * 320;
    const int  lry  = ls >> 3;            // raw row 0..39
    const int  lxq  = ls & 7;             // x quad 0..7
    const int  lgy  = y0 - 4 + lry;
    const int  lgx0 = x0 - 4 + 4 * lxq;   // 16B-aligned quad base
    const bool lactive = (tid < 960);
    const bool lyok = ((unsigned)lgy < (unsigned)N);

    // ---- C (col-sum) decode: 3 fields x 8 y-quads x 32 x = 768 slots (12 waves)
    const int  cf  = tid >> 8;
    const int  cyq = (tid >> 5) & 7;
    const int  cx  = tid & 31;
    const bool cactive = (tid < 768);

    // ---- G decode: thread owns output column (gx,gy)
    const int gx = tid & 31;
    const int gy = tid >> 5;

    const size_t plane = (size_t)N * N;
    const float* tb = t_in + (size_t)b * N * plane;
    const float* pb = p_in + (size_t)b * N * plane;
    float*       ob = out  + (size_t)b * N * plane
                           + (size_t)(y0 + gy) * N + (x0 + gx);

    // loop-invariant row base pointers (y clamped; loads stay guarded by lactive&&lyok)
    const int lgyc = lyok ? lgy : 0;
    const float* const trow = tb + (size_t)lgyc * N;
    const float* const prow = pb + (size_t)lgyc * N;
    const float* const arow = (lf == 1) ? prow : trow;   // wave-uniform a-source select

    float ring_t[9], ring_p[9], ring_tp[9];
    float sum_t = 0.f, sum_p = 0.f, sum_tp = 0.f;
    #pragma unroll
    for (int i = 0; i < 9; ++i) { ring_t[i] = 0.f; ring_p[i] = 0.f; ring_tp[i] = 0.f; }

    const float4 z4 = make_float4(0.f, 0.f, 0.f, 0.f);
    float4 cur0 = z4, cur1 = z4, cur2 = z4;     // row-sum-ready 12 floats for plane i

    // ---- prologue: load + finalize plane 0 (one exposed latency per block)
    {
        const int zp0 = z0 - 4;
        if (((unsigned)zp0 < (unsigned)N) && lactive && lyok) {
            const float* ar = arow + (size_t)zp0 * plane;
            const float* cr = prow + (size_t)zp0 * plane;
            float4 a[3], c[3];
            #pragma unroll
            for (int q = 0; q < 3; ++q) {
                a[q] = z4; c[q] = z4;
                const int gxq = lgx0 + 4 * q;
                if ((unsigned)gxq < (unsigned)N) {
                    a[q] = *(const float4*)(ar + gxq);
                    if (lf == 2) c[q] = *(const float4*)(cr + gxq);
                }
            }
            if (lf == 2) {
                #pragma unroll
                for (int q = 0; q < 3; ++q) {
                    a[q].x *= c[q].x; a[q].y *= c[q].y;
                    a[q].z *= c[q].z; a[q].w *= c[q].w;
                }
            }
            cur0 = a[0]; cur1 = a[1]; cur2 = a[2];
        }
    }

    #pragma unroll 1
    for (int k = 0; k < 4; ++k) {
      #pragma unroll
      for (int r = 0; r < 9; ++r) {
        const int i  = k * 9 + r;
        const int zp = z0 - 4 + i;           // plane i
        const int zn = zp + 1;               // plane i+1
        const bool vi = (i < Z + 8)     && ((unsigned)zp < (unsigned)N);
        const bool vn = (i + 1 < Z + 8) && ((unsigned)zn < (unsigned)N);

        // ---- 1. issue loads for plane i+1 (consumed at step 5) ----
        float4 fa0 = z4, fa1 = z4, fa2 = z4, fc0 = z4, fc1 = z4, fc2 = z4;
        if (vn && lactive && lyok) {
            const float* ar = arow + (size_t)zn * plane;
            const float* cr = prow + (size_t)zn * plane;
            const int g0 = lgx0, g1 = lgx0 + 4, g2 = lgx0 + 8;
            if ((unsigned)g0 < (unsigned)N) {
                fa0 = *(const float4*)(ar + g0);
                if (lf == 2) fc0 = *(const float4*)(cr + g0);
            }
            if ((unsigned)g1 < (unsigned)N) {
                fa1 = *(const float4*)(ar + g1);
                if (lf == 2) fc1 = *(const float4*)(cr + g1);
            }
            if ((unsigned)g2 < (unsigned)N) {
                fa2 = *(const float4*)(ar + g2);
                if (lf == 2) fc2 = *(const float4*)(cr + g2);
            }
        }

        // ---- 2. RowSum(plane i) from cur -> rowT ----
        if (vi && lactive) {
            const float v0 = cur0.x, v1 = cur0.y, v2  = cur0.z, v3  = cur0.w;
            const float v4 = cur1.x, v5 = cur1.y, v6  = cur1.z, v7  = cur1.w;
            const float v8 = cur2.x, v9 = cur2.y, v10 = cur2.z, v11 = cur2.w;
            float s0 = ((v0+v1) + (v2+v3)) + ((v4+v5) + (v6+v7)) + v8;
            float s1 = s0 - v0 + v9;
            float s2 = s1 - v1 + v10;
            float s3 = s2 - v2 + v11;
            float* wp = &rowT[(lf * 32 + 4 * lxq) * RSTRIDE + lry];
            wp[0]           = s0;
            wp[RSTRIDE]     = s1;
            wp[2 * RSTRIDE] = s2;
            wp[3 * RSTRIDE] = s3;
        }
        LDS_BARRIER();

        // ---- 3. ColSum(plane i): rowT -> pcol ----
        if (vi && cactive) {
            const float* rb = &rowT[(cf * 32 + cx) * RSTRIDE + 4 * cyq];
            const float2 u0 = *(const float2*)(rb + 0);
            const float2 u1 = *(const float2*)(rb + 2);
            const float2 u2 = *(const float2*)(rb + 4);
            const float2 u3 = *(const float2*)(rb + 6);
            const float2 u4 = *(const float2*)(rb + 8);
            const float2 u5 = *(const float2*)(rb + 10);
            const float w0=u0.x, w1=u0.y, w2=u1.x,  w3=u1.y;
            const float w4=u2.x, w5=u2.y, w6=u3.x,  w7=u3.y;
            const float w8=u4.x, w9=u4.y, w10=u5.x, w11=u5.y;
            float c0 = ((w0+w1)+(w2+w3)) + ((w4+w5)+(w6+w7)) + w8;
            float c1 = c0 - w0 + w9;
            float c2 = c1 - w1 + w10;
            float c3 = c2 - w2 + w11;
            float* pc = &pcol[cf * 1024 + (4 * cyq) * 32 + cx];
            pc[0]  = c0;
            pc[32] = c1;
            pc[64] = c2;
            pc[96] = c3;
        }
        LDS_BARRIER();

        // ---- 4. Gather(plane i), z-ring (slot r == i%9), output ----
        float Pt = 0.f, Pp = 0.f, Ptp = 0.f;
        if (vi) {
            Pt  = pcol[       gy * 32 + gx];
            Pp  = pcol[1024 + gy * 32 + gx];
            Ptp = pcol[2048 + gy * 32 + gx];
        }
        sum_t  += Pt  - ring_t[r];  ring_t[r]  = Pt;
        sum_p  += Pp  - ring_p[r];  ring_p[r]  = Pp;
        sum_tp += Ptp - ring_tp[r]; ring_tp[r] = Ptp;
        if (i >= 8 && i < Z + 8) {
            const float cross = sum_tp - (sum_p * (1.0f / 729.0f)) * sum_t;
            ob[(size_t)(z0 + i - 8) * plane] = cross * cross + 1e-5f;
        }

        // ---- 5. finalize: cur = (lf==2 ? a*c : a)  (loads have landed by now) ----
        if (vn && lactive) {
            float4 A0 = fa0, A1 = fa1, A2 = fa2;
            if (lf == 2) {
                A0.x *= fc0.x; A0.y *= fc0.y; A0.z *= fc0.z; A0.w *= fc0.w;
                A1.x *= fc1.x; A1.y *= fc1.y; A1.z *= fc1.z; A1.w *= fc1.w;
                A2.x *= fc2.x; A2.y *= fc2.y; A2.z *= fc2.z; A2.w *= fc2.w;
            }
            cur0 = A0; cur1 = A1; cur2 = A2;
        }
      }
    }
}

extern "C" void kernel_launch(void* const* d_in, const int* in_sizes, int n_in,
                              void* d_out, int out_size, void* d_ws, size_t ws_size,
                              hipStream_t stream) {
    const float* y_true = (const float*)d_in[0];
    const float* y_pred = (const float*)d_in[1];
    float* out = (float*)d_out;
    dim3 grid(512);
    dim3 block(1024);
    hipLaunchKernelGGL(lncc_kernel, grid, block, 0, stream, y_true, y_pred, out);
}